// Round 10
// baseline (6319.292 us; speedup 1.0000x reference)
//
#include <hip/hip_runtime.h>

// ---------------------------------------------------------------------------
// Persistent fused 2-layer LSTM + FC for MI355X — v10: v6 + single 32-load
// drain (v6 paid two serialized 16-load LLC drains per step).
//  - 128 WGs x 256 threads (4 waves), 4 batch-groups x 32 WGs. 1 WG/CU.
//  - Wave roles (v6): wv0/wv1 = L0 units [hb,hb+8) full-K 576;
//    wv2/wv3 = L1 units [hb,hb+8) full-K 1024. hb = (wid&31)*16 + (wv&1)*8.
//  - Weights resident in VGPR/AGPR (256-thr WG = 1 wave/SIMD = 512-reg
//    unified budget; 512-thr WGs cap at 128 VGPR and spill — v4/v8 lesson).
//  - h exchange: u32 = fp16|(tag<<16), 3-slot agent-scope ring, speculative
//    bulk read + per-word retry, double-buffered LDS staging, 1 barrier/step.
//  - v10 deltas: (1) ONE drain: all 32 tagged u64 loads issued back-to-back,
//    verified together (u64 mask compare), only stale words re-read;
//    (2) x prefetch issued AFTER ring loads (ring owns VMEM queue head).
// ---------------------------------------------------------------------------

#define H      512
#define T_SEQ  1024
#define DIN    64
#define STEPS  1025

#define SLOT_U32 16384           // [2 layers][16 batch][512 units] tagged u32
#define GRP_U32  49152           // 3 slots
#define WS_BYTES (4 * GRP_U32 * 4)

typedef _Float16 f16x8 __attribute__((ext_vector_type(8)));
typedef float    f32x4 __attribute__((ext_vector_type(4)));
typedef unsigned long long u64t;

__device__ __forceinline__ u64t ld_u64(const u64t* p) {
  return __hip_atomic_load((u64t*)p, __ATOMIC_RELAXED, __HIP_MEMORY_SCOPE_AGENT);
}
__device__ __forceinline__ void st_u32(unsigned* p, unsigned v) {
  __hip_atomic_store(p, v, __ATOMIC_RELAXED, __HIP_MEMORY_SCOPE_AGENT);
}
__device__ __forceinline__ f16x8 pk8(float4 a, float4 b) {
  f16x8 r;
  r[0] = (_Float16)a.x; r[1] = (_Float16)a.y; r[2] = (_Float16)a.z; r[3] = (_Float16)a.w;
  r[4] = (_Float16)b.x; r[5] = (_Float16)b.y; r[6] = (_Float16)b.z; r[7] = (_Float16)b.w;
  return r;
}
__device__ __forceinline__ f16x8 cvt8(const float* p) {
  return pk8(*(const float4*)p, *(const float4*)(p + 4));
}
__device__ __forceinline__ f32x4 mfma16(f16x8 a, f16x8 b, f32x4 c) {
  return __builtin_amdgcn_mfma_f32_16x16x32_f16(a, b, c, 0, 0, 0);
}
__device__ __forceinline__ float rcpf_(float x) {
#if __has_builtin(__builtin_amdgcn_rcpf)
  return __builtin_amdgcn_rcpf(x);
#else
  return 1.0f / x;
#endif
}
__device__ __forceinline__ float sigm(float x) {
  x = fminf(fmaxf(x, -30.f), 30.f);
  return rcpf_(1.f + __expf(-x));
}
__device__ __forceinline__ float tanhx(float x) {
  x = fminf(fmaxf(x, -15.f), 15.f);
  float e = __expf(2.f * x);
  return (e - 1.f) * rcpf_(e + 1.f);
}
__device__ __forceinline__ unsigned payload(u64t v) {
  return ((unsigned)v & 0xffffu) | ((unsigned)(v >> 32) << 16);
}

__global__ __launch_bounds__(256, 1)
void lstm_fused(const float* __restrict__ x,
                const float* __restrict__ Wih0, const float* __restrict__ Whh0,
                const float* __restrict__ bih0, const float* __restrict__ bhh0,
                const float* __restrict__ Wih1, const float* __restrict__ Whh1,
                const float* __restrict__ bih1, const float* __restrict__ bhh1,
                const float* __restrict__ fcw,  const float* __restrict__ fcb,
                float* __restrict__ out, unsigned* __restrict__ ws)
{
  // double-buffered staged h: [buf][2 layers][16 batch][260 u32]
  __shared__ unsigned sH[2][8320];

  const int tid  = threadIdx.x;
  const int wid  = blockIdx.x;
  const int g    = wid >> 5;           // batch group 0..3
  const int w    = wid & 31;           // WG within group
  const int wv   = tid >> 6;           // wave 0..3
  const int lane = tid & 63;
  const int bcol = lane & 15;          // MFMA N col = batch-in-group
  const int kgrp = lane >> 4;
  const int layer = wv >> 1;
  const int hb    = w * 16 + (wv & 1) * 8;   // 8 units of this wave

  unsigned* gbase = ws + g * GRP_U32;

  // ---- resident weights: 2 M-tiles (units hb..+3, hb+4..+7), full K.
  //      M rows gate-interleaved: row m -> gate m&3, unit hb + (m>>2).
  const int src_m = lane & 15;
  const int gr0 = (src_m & 3) * H + hb + (src_m >> 2);   // PyTorch gate row
  const int gr1 = gr0 + 4;
  f16x8 wA[2][32];
  if (layer == 0) {                    // K = 64(x) + 512(h0): frags 0..17
    #pragma unroll
    for (int f = 0; f < 18; ++f) {
      const float *p0, *p1;
      if (f < 2) {
        p0 = Wih0 + (size_t)gr0 * DIN + f * 32 + kgrp * 8;
        p1 = Wih0 + (size_t)gr1 * DIN + f * 32 + kgrp * 8;
      } else {
        p0 = Whh0 + (size_t)gr0 * H + (f - 2) * 32 + kgrp * 8;
        p1 = Whh0 + (size_t)gr1 * H + (f - 2) * 32 + kgrp * 8;
      }
      wA[0][f] = cvt8(p0); wA[1][f] = cvt8(p1);
    }
  } else {                             // K = 512(h0) + 512(h1): frags 0..31
    #pragma unroll
    for (int f = 0; f < 16; ++f) {
      int col = f * 32 + kgrp * 8;
      wA[0][f] = cvt8(Wih1 + (size_t)gr0 * H + col);
      wA[1][f] = cvt8(Wih1 + (size_t)gr1 * H + col);
    }
    #pragma unroll
    for (int f = 16; f < 32; ++f) {
      int col = (f - 16) * 32 + kgrp * 8;
      wA[0][f] = cvt8(Whh1 + (size_t)gr0 * H + col);
      wA[1][f] = cvt8(Whh1 + (size_t)gr1 * H + col);
    }
  }
  float bias[2][4];
  {
    const float* bi = layer ? bih1 : bih0;
    const float* bh = layer ? bhh1 : bhh0;
    #pragma unroll
    for (int t = 0; t < 2; ++t)
      #pragma unroll
      for (int rr = 0; rr < 4; ++rr) {
        int u = hb + t * 4 + kgrp;
        bias[t][rr] = bi[rr * H + u] + bh[rr * H + u];
      }
  }

  // zero both staging buffers once (step 0 reads zeros as h_{-1})
  for (int i = tid; i < 2 * 8320; i += 256) ((unsigned*)sH)[i] = 0;
  __syncthreads();

  float cst0 = 0.f, cst1 = 0.f;
  unsigned spins = 0;
  const int rowb = bcol * 1040 + kgrp * 16;   // byte offset of B-frag row

  for (int s = 0; s < STEPS; ++s) {
    // ---- single-drain bulk read: all 32 tagged u64 loads issued first
    u64t v[32];
    const u64t* src = (const u64t*)(gbase + ((s - 1) % 3) * SLOT_U32);
    if (s > 0) {
      #pragma unroll
      for (int i = 0; i < 32; ++i) v[i] = ld_u64(src + tid + i * 256);
    }
    // x prefetch for L0 waves (after ring issue — ring owns queue head)
    float4 xr0 = {0,0,0,0}, xr1 = xr0, xr2 = xr0, xr3 = xr0;
    if (layer == 0) {
      int t = (s < T_SEQ) ? s : (T_SEQ - 1);
      const float* xp = x + ((size_t)((g * 16 + bcol) * T_SEQ + t)) * DIN + kgrp * 8;
      xr0 = *(const float4*)xp;        xr1 = *(const float4*)(xp + 4);
      xr2 = *(const float4*)(xp + 32); xr3 = *(const float4*)(xp + 36);
    }
    if (s > 0) {
      const unsigned want = (unsigned)s;
      const u64t want64 = ((u64t)want << 48) | ((u64t)want << 16);
      for (;;) {
        unsigned bad = 0;
        #pragma unroll
        for (int i = 0; i < 32; ++i)
          if ((v[i] ^ want64) & 0xFFFF0000FFFF0000ull) bad |= (1u << i);
        if (!bad) break;
        if (++spins > 8000000u) break;         // bounded anti-hang guard
        #pragma unroll
        for (int i = 0; i < 32; ++i)
          if (bad & (1u << i)) v[i] = ld_u64(src + tid + i * 256);
      }
      unsigned* db = sH[s & 1];
      #pragma unroll
      for (int i = 0; i < 32; ++i) {
        int j = tid + i * 256;                 // [2][16][256] u64 index
        db[(j >> 12) * 4160 + ((j >> 8) & 15) * 260 + (j & 255)] = payload(v[i]);
      }
    }
    __syncthreads();                           // staged; WAR handled by dbuf

    const bool act = layer ? (s > 0) : (s < T_SEQ);
    float hv0 = 0.f, hv1 = 0.f;
    if (act) {
      f32x4 acc0 = {0,0,0,0}, acc1 = {0,0,0,0};
      const char* cur = (const char*)sH[s & 1];
      if (layer == 0) {
        f16x8 b0 = pk8(xr0, xr1);
        acc0 = mfma16(wA[0][0], b0, acc0); acc1 = mfma16(wA[1][0], b0, acc1);
        f16x8 b1 = pk8(xr2, xr3);
        acc0 = mfma16(wA[0][1], b1, acc0); acc1 = mfma16(wA[1][1], b1, acc1);
        #pragma unroll
        for (int f = 2; f < 18; ++f) {
          f16x8 bf = *(const f16x8*)(cur + rowb + (f - 2) * 64);
          acc0 = mfma16(wA[0][f], bf, acc0); acc1 = mfma16(wA[1][f], bf, acc1);
        }
      } else {
        #pragma unroll
        for (int f = 0; f < 16; ++f) {
          f16x8 bf = *(const f16x8*)(cur + rowb + f * 64);
          acc0 = mfma16(wA[0][f], bf, acc0); acc1 = mfma16(wA[1][f], bf, acc1);
        }
        #pragma unroll
        for (int f = 16; f < 32; ++f) {
          f16x8 bf = *(const f16x8*)(cur + 16640 + rowb + (f - 16) * 64);
          acc0 = mfma16(wA[0][f], bf, acc0); acc1 = mfma16(wA[1][f], bf, acc1);
        }
      }
      {
        float ii = sigm(acc0[0] + bias[0][0]);
        float ff = sigm(acc0[1] + bias[0][1]);
        float gg = tanhx(acc0[2] + bias[0][2]);
        float oo = sigm(acc0[3] + bias[0][3]);
        cst0 = ff * cst0 + ii * gg;
        hv0 = oo * tanhx(cst0);
      }
      {
        float ii = sigm(acc1[0] + bias[1][0]);
        float ff = sigm(acc1[1] + bias[1][1]);
        float gg = tanhx(acc1[2] + bias[1][2]);
        float oo = sigm(acc1[3] + bias[1][3]);
        cst1 = ff * cst1 + ii * gg;
        hv1 = oo * tanhx(cst1);
      }
    }
    const bool produce = layer ? true : (s < T_SEQ);   // L1 emits zeros at s=0
    if (produce) {
      unsigned tag = (unsigned)(s + 1) << 16;
      unsigned u0 = (unsigned)__builtin_bit_cast(unsigned short, (_Float16)hv0);
      unsigned u1 = (unsigned)__builtin_bit_cast(unsigned short, (_Float16)hv1);
      unsigned* dst = gbase + (s % 3) * SLOT_U32 + layer * 8192
                    + bcol * 512 + hb + kgrp;
      st_u32(dst,     u0 | tag);               // unit hb+kgrp
      st_u32(dst + 4, u1 | tag);               // unit hb+kgrp+4
    }
    // no trailing barrier: next step writes the OTHER LDS buffer
  }

  __syncthreads();                             // main-loop LDS reads done

  // ---- FC epilogue: out = relu([h0_T; h1_T] @ fc_w^T + fc_b), [128][1024]
  {
    const int rt = wid >> 4, ct = wid & 15;    // 8 row-tiles x 16 col-tiles
    const int sg = rt & 3;
    const bool isH1 = (rt >= 4);
    // h0_T: step 1023 -> slot 0, tag 1024; h1_T: step 1024 -> slot 1, tag 1025
    const unsigned want = isH1 ? (unsigned)STEPS : (unsigned)(STEPS - 1);
    const int     slot  = isH1 ? 1 : 0;
    const u64t* src = (const u64t*)(ws + sg * GRP_U32 + slot * SLOT_U32
                                    + (isH1 ? 8192 : 0));
    u64t v[16];
    #pragma unroll
    for (int i = 0; i < 16; ++i) v[i] = ld_u64(src + tid + i * 256);
    for (;;) {
      unsigned bad = 0;
      #pragma unroll
      for (int i = 0; i < 16; ++i) {
        unsigned lo = (unsigned)v[i], hi = (unsigned)(v[i] >> 32);
        if (((lo >> 16) ^ want) | ((hi >> 16) ^ want)) bad |= (1u << i);
      }
      if (!bad) break;
      if (++spins > 8000000u) break;
      #pragma unroll
      for (int i = 0; i < 16; ++i)
        if (bad & (1u << i)) v[i] = ld_u64(src + tid + i * 256);
    }
    #pragma unroll
    for (int i = 0; i < 16; ++i) {
      int j = tid + i * 256;                   // [16 batch][256 pairs]
      sH[0][(j >> 8) * 260 + (j & 255)] = payload(v[i]);
    }
    __syncthreads();
    const int col = ct * 64 + wv * 16 + bcol;
    f32x4 a0 = {0,0,0,0}, a1 = {0,0,0,0};
    #pragma unroll
    for (int f = 0; f < 16; ++f) {             // K = 512
      f16x8 af = *(const f16x8*)((const char*)sH[0] + rowb + f * 64);
      f16x8 bf = cvt8(fcw + (size_t)col * H + f * 32 + kgrp * 8);
      if (f & 1) a1 = mfma16(af, bf, a1); else a0 = mfma16(af, bf, a0);
    }
    f32x4 a = a0 + a1;
    const float fb = fcb[col];
    #pragma unroll
    for (int rr = 0; rr < 4; ++rr) {
      int row = rt * 16 + kgrp * 4 + rr;
      float v2 = a[rr] + fb;
      out[(size_t)row * 1024 + col] = v2 > 0.f ? v2 : 0.f;
    }
  }
}

extern "C" void kernel_launch(void* const* d_in, const int* in_sizes, int n_in,
                              void* d_out, int out_size, void* d_ws, size_t ws_size,
                              hipStream_t stream) {
  const float* x    = (const float*)d_in[0];
  const float* Wih0 = (const float*)d_in[1];
  const float* Whh0 = (const float*)d_in[2];
  const float* bih0 = (const float*)d_in[3];
  const float* bhh0 = (const float*)d_in[4];
  const float* Wih1 = (const float*)d_in[5];
  const float* Whh1 = (const float*)d_in[6];
  const float* bih1 = (const float*)d_in[7];
  const float* bhh1 = (const float*)d_in[8];
  const float* fcw  = (const float*)d_in[9];
  const float* fcb  = (const float*)d_in[10];
  (void)in_sizes; (void)n_in; (void)out_size; (void)ws_size;

  // zero tag space every call (tag 0 never matches any wanted tag >= 1)
  hipMemsetAsync(d_ws, 0, WS_BYTES, stream);
  lstm_fused<<<dim3(128), dim3(256), 0, stream>>>(
      x, Wih0, Whh0, bih0, bhh0, Wih1, Whh1, bih1, bhh1, fcw, fcb,
      (float*)d_out, (unsigned*)d_ws);
}

// Round 11
// 4928.499 us; speedup vs baseline: 1.2822x; 1.2822x over previous
//
#include <hip/hip_runtime.h>

// ---------------------------------------------------------------------------
// Persistent fused 2-layer LSTM + FC for MI355X — v11: packed untagged h +
// vmcnt-fenced per-wave progress tags.
//  - Geometry = v6 (best so far): 128 WGs x 256 thr (4 waves), 4 groups x 32
//    WGs, 1 WG/CU. wv0/wv1 = L0 (8 units full-K 576), wv2/wv3 = L1 (8 units
//    full-K 1024). Weights resident (v6's proven ~204-VGPR envelope).
//  - h ring: u32 = packed {fp16 even-unit, fp16 odd-unit} (NO tag) =>
//    32KB/group/step (half of v6) => LLC broadcast service 8->4 MB/step.
//  - Ordering: producer wave stores data, s_waitcnt vmcnt(0) (write-ack at
//    coherence point; the data->flag pattern that passed 1025-step
//    validation in v1), lane0 stores monotonic prog tag. Consumer: 128
//    threads poll 128 tags, barrier, ONE unconditional 16xu64 bulk read
//    (no verify loop, no retries, no repack bit-ops).
//  - Unit pairing (v8's even/odd A-tiles): lane kgrp owns units hb+2k,
//    hb+2k+1 -> one packed u32 store per lane.
// ---------------------------------------------------------------------------

#define H      512
#define T_SEQ  1024
#define DIN    64
#define STEPS  1025

#define SLOT_U32 8192            // [2 layers][16 batch][256 packed u32] = 32KB
#define PROG_OFF 24576           // 3 slots
#define GRP_U32  24832           // +128 prog +pad
#define WS_BYTES (4 * GRP_U32 * 4)

typedef _Float16 f16x8 __attribute__((ext_vector_type(8)));
typedef float    f32x4 __attribute__((ext_vector_type(4)));
typedef unsigned long long u64t;

__device__ __forceinline__ u64t ld_u64(const u64t* p) {
  return __hip_atomic_load((u64t*)p, __ATOMIC_RELAXED, __HIP_MEMORY_SCOPE_AGENT);
}
__device__ __forceinline__ unsigned ld_u32a(const unsigned* p) {
  return __hip_atomic_load((unsigned*)p, __ATOMIC_RELAXED, __HIP_MEMORY_SCOPE_AGENT);
}
__device__ __forceinline__ void st_u32(unsigned* p, unsigned v) {
  __hip_atomic_store(p, v, __ATOMIC_RELAXED, __HIP_MEMORY_SCOPE_AGENT);
}
__device__ __forceinline__ f16x8 pk8(float4 a, float4 b) {
  f16x8 r;
  r[0] = (_Float16)a.x; r[1] = (_Float16)a.y; r[2] = (_Float16)a.z; r[3] = (_Float16)a.w;
  r[4] = (_Float16)b.x; r[5] = (_Float16)b.y; r[6] = (_Float16)b.z; r[7] = (_Float16)b.w;
  return r;
}
__device__ __forceinline__ f16x8 cvt8(const float* p) {
  return pk8(*(const float4*)p, *(const float4*)(p + 4));
}
__device__ __forceinline__ f32x4 mfma16(f16x8 a, f16x8 b, f32x4 c) {
  return __builtin_amdgcn_mfma_f32_16x16x32_f16(a, b, c, 0, 0, 0);
}
__device__ __forceinline__ float rcpf_(float x) {
#if __has_builtin(__builtin_amdgcn_rcpf)
  return __builtin_amdgcn_rcpf(x);
#else
  return 1.0f / x;
#endif
}
__device__ __forceinline__ float sigm(float x) {
  x = fminf(fmaxf(x, -30.f), 30.f);
  return rcpf_(1.f + __expf(-x));
}
__device__ __forceinline__ float tanhx(float x) {
  x = fminf(fmaxf(x, -15.f), 15.f);
  float e = __expf(2.f * x);
  return (e - 1.f) * rcpf_(e + 1.f);
}

__global__ __launch_bounds__(256, 1)
void lstm_fused(const float* __restrict__ x,
                const float* __restrict__ Wih0, const float* __restrict__ Whh0,
                const float* __restrict__ bih0, const float* __restrict__ bhh0,
                const float* __restrict__ Wih1, const float* __restrict__ Whh1,
                const float* __restrict__ bih1, const float* __restrict__ bhh1,
                const float* __restrict__ fcw,  const float* __restrict__ fcb,
                float* __restrict__ out, unsigned* __restrict__ ws)
{
  // double-buffered staged h: [buf][2 layers][16 batch][260 u32]
  __shared__ unsigned sH[2][8320];

  const int tid  = threadIdx.x;
  const int wid  = blockIdx.x;
  const int g    = wid >> 5;           // batch group 0..3
  const int w    = wid & 31;           // WG within group
  const int wv   = tid >> 6;           // wave 0..3
  const int lane = tid & 63;
  const int bcol = lane & 15;          // MFMA N col = batch-in-group
  const int kgrp = lane >> 4;
  const int layer = wv >> 1;
  const int hb    = w * 16 + (wv & 1) * 8;   // 8 units of this wave

  unsigned* gbase = ws + g * GRP_U32;
  unsigned* prog  = gbase + PROG_OFF;  // 128 monotonic tags: [w][wv]

  // ---- resident weights: 2 M-tiles = even units (hb+2k) / odd (hb+2k+1).
  //      M rows gate-interleaved: row m -> gate m&3, unit hb + 2*(m>>2)(+1).
  const int src_m = lane & 15;
  const int gr0 = (src_m & 3) * H + hb + 2 * (src_m >> 2);  // even-unit row
  const int gr1 = gr0 + 1;                                  // odd-unit row
  f16x8 wA[2][32];
  if (layer == 0) {                    // K = 64(x) + 512(h0): frags 0..17
    #pragma unroll
    for (int f = 0; f < 18; ++f) {
      const float *p0, *p1;
      if (f < 2) {
        p0 = Wih0 + (size_t)gr0 * DIN + f * 32 + kgrp * 8;
        p1 = Wih0 + (size_t)gr1 * DIN + f * 32 + kgrp * 8;
      } else {
        p0 = Whh0 + (size_t)gr0 * H + (f - 2) * 32 + kgrp * 8;
        p1 = Whh0 + (size_t)gr1 * H + (f - 2) * 32 + kgrp * 8;
      }
      wA[0][f] = cvt8(p0); wA[1][f] = cvt8(p1);
    }
  } else {                             // K = 512(h0) + 512(h1): frags 0..31
    #pragma unroll
    for (int f = 0; f < 16; ++f) {
      int col = f * 32 + kgrp * 8;
      wA[0][f] = cvt8(Wih1 + (size_t)gr0 * H + col);
      wA[1][f] = cvt8(Wih1 + (size_t)gr1 * H + col);
    }
    #pragma unroll
    for (int f = 16; f < 32; ++f) {
      int col = (f - 16) * 32 + kgrp * 8;
      wA[0][f] = cvt8(Whh1 + (size_t)gr0 * H + col);
      wA[1][f] = cvt8(Whh1 + (size_t)gr1 * H + col);
    }
  }
  float bias[2][4];
  {
    const float* bi = layer ? bih1 : bih0;
    const float* bh = layer ? bhh1 : bhh0;
    const int u0 = hb + 2 * kgrp, u1 = u0 + 1;
    #pragma unroll
    for (int rr = 0; rr < 4; ++rr) {
      bias[0][rr] = bi[rr * H + u0] + bh[rr * H + u0];
      bias[1][rr] = bi[rr * H + u1] + bh[rr * H + u1];
    }
  }

  // zero both staging buffers once (step 0 reads zeros as h_{-1})
  for (int i = tid; i < 2 * 8320; i += 256) ((unsigned*)sH)[i] = 0;
  __syncthreads();

  float cst0 = 0.f, cst1 = 0.f;
  unsigned spins = 0;
  const int rowb = bcol * 1040 + kgrp * 16;   // byte offset of B-frag row

  for (int s = 0; s < STEPS; ++s) {
    // x prefetch for L0 waves (overlaps the tag poll)
    float4 xr0 = {0,0,0,0}, xr1 = xr0, xr2 = xr0, xr3 = xr0;
    if (layer == 0) {
      int t = (s < T_SEQ) ? s : (T_SEQ - 1);
      const float* xp = x + ((size_t)((g * 16 + bcol) * T_SEQ + t)) * DIN + kgrp * 8;
      xr0 = *(const float4*)xp;        xr1 = *(const float4*)(xp + 4);
      xr2 = *(const float4*)(xp + 32); xr3 = *(const float4*)(xp + 36);
    }
    if (s > 0) {
      // ---- phase 1: tag poll (128 threads, 128 distinct words)
      if (tid < 128) {
        const unsigned* tp = prog + tid;
        unsigned tv = ld_u32a(tp);
        while (tv < (unsigned)s) {
          if (++spins > 8000000u) break;       // bounded anti-hang guard
          tv = ld_u32a(tp);
        }
      }
      __syncthreads();                         // all producers done
      // ---- phase 2: ONE unconditional bulk read (32KB, 16 u64/thread)
      const u64t* src = (const u64t*)(gbase + ((s - 1) % 3) * SLOT_U32);
      u64t v[16];
      #pragma unroll
      for (int i = 0; i < 16; ++i) v[i] = ld_u64(src + tid + i * 256);
      u64t* db = (u64t*)sH[s & 1];
      #pragma unroll
      for (int i = 0; i < 16; ++i) {
        int j = tid + i * 256;                 // u64 index in [2][16][128]
        db[(j >> 11) * 2080 + ((j >> 7) & 15) * 130 + (j & 127)] = v[i];
      }
    }
    __syncthreads();                           // staged; WAR handled by dbuf

    const bool act = layer ? (s > 0) : (s < T_SEQ);
    float hv0 = 0.f, hv1 = 0.f;
    if (act) {
      f32x4 acc0 = {0,0,0,0}, acc1 = {0,0,0,0};
      const char* cur = (const char*)sH[s & 1];
      if (layer == 0) {
        f16x8 b0 = pk8(xr0, xr1);
        acc0 = mfma16(wA[0][0], b0, acc0); acc1 = mfma16(wA[1][0], b0, acc1);
        f16x8 b1 = pk8(xr2, xr3);
        acc0 = mfma16(wA[0][1], b1, acc0); acc1 = mfma16(wA[1][1], b1, acc1);
        #pragma unroll
        for (int f = 2; f < 18; ++f) {
          f16x8 bf = *(const f16x8*)(cur + rowb + (f - 2) * 64);
          acc0 = mfma16(wA[0][f], bf, acc0); acc1 = mfma16(wA[1][f], bf, acc1);
        }
      } else {
        #pragma unroll
        for (int f = 0; f < 16; ++f) {
          f16x8 bf = *(const f16x8*)(cur + rowb + f * 64);
          acc0 = mfma16(wA[0][f], bf, acc0); acc1 = mfma16(wA[1][f], bf, acc1);
        }
        #pragma unroll
        for (int f = 16; f < 32; ++f) {
          f16x8 bf = *(const f16x8*)(cur + 16640 + rowb + (f - 16) * 64);
          acc0 = mfma16(wA[0][f], bf, acc0); acc1 = mfma16(wA[1][f], bf, acc1);
        }
      }
      {
        float ii = sigm(acc0[0] + bias[0][0]);
        float ff = sigm(acc0[1] + bias[0][1]);
        float gg = tanhx(acc0[2] + bias[0][2]);
        float oo = sigm(acc0[3] + bias[0][3]);
        cst0 = ff * cst0 + ii * gg;
        hv0 = oo * tanhx(cst0);                // even unit hb+2k
      }
      {
        float ii = sigm(acc1[0] + bias[1][0]);
        float ff = sigm(acc1[1] + bias[1][1]);
        float gg = tanhx(acc1[2] + bias[1][2]);
        float oo = sigm(acc1[3] + bias[1][3]);
        cst1 = ff * cst1 + ii * gg;
        hv1 = oo * tanhx(cst1);                // odd unit hb+2k+1
      }
    }
    const bool produce = layer ? true : (s < T_SEQ);   // L1 emits zeros at s=0
    if (produce) {
      unsigned e = (unsigned)__builtin_bit_cast(unsigned short, (_Float16)hv0);
      unsigned o = (unsigned)__builtin_bit_cast(unsigned short, (_Float16)hv1);
      unsigned* dst = gbase + (s % 3) * SLOT_U32 + layer * 4096
                    + bcol * 256 + (hb >> 1) + kgrp;
      st_u32(dst, e | (o << 16));              // packed pair, no tag
    }
    // data at coherence point before tag (v1-proven data->flag ordering)
    asm volatile("s_waitcnt vmcnt(0)" ::: "memory");
    if (lane == 0) st_u32(prog + (w << 2) + wv, (unsigned)(s + 1));
    // no trailing barrier: next step writes the OTHER LDS buffer
  }

  __syncthreads();                             // main-loop LDS reads done

  // ---- FC epilogue: out = relu([h0_T; h1_T] @ fc_w^T + fc_b), [128][1024]
  {
    const int rt = wid >> 4, ct = wid & 15;    // 8 row-tiles x 16 col-tiles
    const int sg = rt & 3;
    const bool isH1 = (rt >= 4);
    // h0_T = h0(1023): stored step 1023 -> slot 0; h1_T = h1(1023): step 1024 -> slot 1
    unsigned* sprog = ws + sg * GRP_U32 + PROG_OFF;
    if (tid < 128) {
      const unsigned* tp = sprog + tid;
      unsigned tv = ld_u32a(tp);
      while (tv < (unsigned)STEPS) {
        if (++spins > 8000000u) break;
        tv = ld_u32a(tp);
      }
    }
    __syncthreads();
    const u64t* src = (const u64t*)(ws + sg * GRP_U32
                                    + (isH1 ? (1 * SLOT_U32 + 4096) : 0));
    u64t v[8];
    #pragma unroll
    for (int i = 0; i < 8; ++i) v[i] = ld_u64(src + tid + i * 256);
    u64t* db = (u64t*)sH[0];
    #pragma unroll
    for (int i = 0; i < 8; ++i) {
      int j = tid + i * 256;                   // u64 index in [16][128]
      db[(j >> 7) * 130 + (j & 127)] = v[i];
    }
    __syncthreads();
    const int col = ct * 64 + wv * 16 + bcol;
    f32x4 a0 = {0,0,0,0}, a1 = {0,0,0,0};
    #pragma unroll
    for (int f = 0; f < 16; ++f) {             // K = 512
      f16x8 af = *(const f16x8*)((const char*)sH[0] + rowb + f * 64);
      f16x8 bf = cvt8(fcw + (size_t)col * H + f * 32 + kgrp * 8);
      if (f & 1) a1 = mfma16(af, bf, a1); else a0 = mfma16(af, bf, a0);
    }
    f32x4 a = a0 + a1;
    const float fb = fcb[col];
    #pragma unroll
    for (int rr = 0; rr < 4; ++rr) {
      int row = rt * 16 + kgrp * 4 + rr;
      float v2 = a[rr] + fb;
      out[(size_t)row * 1024 + col] = v2 > 0.f ? v2 : 0.f;
    }
  }
}

extern "C" void kernel_launch(void* const* d_in, const int* in_sizes, int n_in,
                              void* d_out, int out_size, void* d_ws, size_t ws_size,
                              hipStream_t stream) {
  const float* x    = (const float*)d_in[0];
  const float* Wih0 = (const float*)d_in[1];
  const float* Whh0 = (const float*)d_in[2];
  const float* bih0 = (const float*)d_in[3];
  const float* bhh0 = (const float*)d_in[4];
  const float* Wih1 = (const float*)d_in[5];
  const float* Whh1 = (const float*)d_in[6];
  const float* bih1 = (const float*)d_in[7];
  const float* bhh1 = (const float*)d_in[8];
  const float* fcw  = (const float*)d_in[9];
  const float* fcb  = (const float*)d_in[10];
  (void)in_sizes; (void)n_in; (void)out_size; (void)ws_size;

  // zero ring + prog every call (prog 0 < any wanted tag >= 1)
  hipMemsetAsync(d_ws, 0, WS_BYTES, stream);
  lstm_fused<<<dim3(128), dim3(256), 0, stream>>>(
      x, Wih0, Whh0, bih0, bhh0, Wih1, Whh1, bih1, bhh1, fcw, fcb,
      (float*)d_out, (unsigned*)d_ws);
}

// Round 12
// 4215.631 us; speedup vs baseline: 1.4990x; 1.1691x over previous
//
#include <hip/hip_runtime.h>

// ---------------------------------------------------------------------------
// Persistent fused 2-layer LSTM + FC for MI355X — v6 (proven best: 4220 us).
// Resubmitted verbatim after v7-v11 exploration all regressed or was neutral:
//  - v7 (decoupled layer domains): 4539 — cross-layer jitter wasn't the cost.
//  - v8 (512-thr WGs): 6058 — 128-VGPR cap => weight spill (toolchain rule:
//    weight-resident designs need 256-thr WGs).
//  - v9 (8 groups x 8 batches, 32KB slots): 4645 — slot width exonerated.
//  - v10 (single 32-load drain): 6319 — early h1 reads are stale => extra
//    full re-read rounds; v6's h0-drain-then-h1-drain ordering is optimal
//    (h1 read lands exactly when the slower L1 producers finish).
//  - v11 (packed untagged + vmcnt-fenced tags): 4928 — halved LLC traffic
//    (FETCH 1.1GB->0.6GB) with ZERO time gain: bandwidth model falsified;
//    the serialized poll->barrier->bulk structure costs one extra RTT vs
//    v6's tagged-data speculative read (discovery+data in one round trip).
// Structure:
//  - 128 WGs x 256 threads (4 waves), 4 batch-groups x 32 WGs, 1 WG/CU.
//  - wv0/wv1 = L0 units [hb,hb+8) full-K 576; wv2/wv3 = L1 units full-K 1024.
//    Weights resident in VGPRs (204 VGPR envelope, no spill).
//  - h exchange: u32 = fp16|(tag<<16), 3-slot agent-scope ring, speculative
//    bulk read + per-word retry, double-buffered LDS staging, 1 barrier/step.
// ---------------------------------------------------------------------------

#define H      512
#define T_SEQ  1024
#define DIN    64
#define STEPS  1025

#define SLOT_U32 16384           // [2 layers][16 batch][512 units] tagged u32
#define GRP_U32  49152           // 3 slots
#define WS_BYTES (4 * GRP_U32 * 4)

typedef _Float16 f16x8 __attribute__((ext_vector_type(8)));
typedef float    f32x4 __attribute__((ext_vector_type(4)));

__device__ __forceinline__ unsigned long long ld_u64(const unsigned long long* p) {
  return __hip_atomic_load((unsigned long long*)p, __ATOMIC_RELAXED, __HIP_MEMORY_SCOPE_AGENT);
}
__device__ __forceinline__ void st_u32(unsigned* p, unsigned v) {
  __hip_atomic_store(p, v, __ATOMIC_RELAXED, __HIP_MEMORY_SCOPE_AGENT);
}
__device__ __forceinline__ f16x8 pk8(float4 a, float4 b) {
  f16x8 r;
  r[0] = (_Float16)a.x; r[1] = (_Float16)a.y; r[2] = (_Float16)a.z; r[3] = (_Float16)a.w;
  r[4] = (_Float16)b.x; r[5] = (_Float16)b.y; r[6] = (_Float16)b.z; r[7] = (_Float16)b.w;
  return r;
}
__device__ __forceinline__ f16x8 cvt8(const float* p) {
  return pk8(*(const float4*)p, *(const float4*)(p + 4));
}
__device__ __forceinline__ f32x4 mfma16(f16x8 a, f16x8 b, f32x4 c) {
  return __builtin_amdgcn_mfma_f32_16x16x32_f16(a, b, c, 0, 0, 0);
}
__device__ __forceinline__ float rcpf_(float x) {
#if __has_builtin(__builtin_amdgcn_rcpf)
  return __builtin_amdgcn_rcpf(x);
#else
  return 1.0f / x;
#endif
}
__device__ __forceinline__ float sigm(float x) {
  x = fminf(fmaxf(x, -30.f), 30.f);
  return rcpf_(1.f + __expf(-x));
}
__device__ __forceinline__ float tanhx(float x) {
  x = fminf(fmaxf(x, -15.f), 15.f);
  float e = __expf(2.f * x);
  return (e - 1.f) * rcpf_(e + 1.f);
}

__global__ __launch_bounds__(256, 1)
void lstm_fused(const float* __restrict__ x,
                const float* __restrict__ Wih0, const float* __restrict__ Whh0,
                const float* __restrict__ bih0, const float* __restrict__ bhh0,
                const float* __restrict__ Wih1, const float* __restrict__ Whh1,
                const float* __restrict__ bih1, const float* __restrict__ bhh1,
                const float* __restrict__ fcw,  const float* __restrict__ fcb,
                float* __restrict__ out, unsigned* __restrict__ ws)
{
  // double-buffered staged h: [buf][2 layers][16 batch][260 u32]
  __shared__ unsigned sH[2][8320];

  const int tid  = threadIdx.x;
  const int wid  = blockIdx.x;
  const int g    = wid >> 5;           // batch group 0..3
  const int w    = wid & 31;           // WG within group
  const int wv   = tid >> 6;           // wave 0..3
  const int lane = tid & 63;
  const int bcol = lane & 15;          // MFMA N col = batch-in-group
  const int kgrp = lane >> 4;
  const int layer = wv >> 1;
  const int hb    = w * 16 + (wv & 1) * 8;   // 8 units of this wave

  unsigned* gbase = ws + g * GRP_U32;

  // ---- resident weights: 2 M-tiles (units hb..+3, hb+4..+7), full K.
  //      M rows gate-interleaved: row m -> gate m&3, unit hb + (m>>2).
  const int src_m = lane & 15;
  const int gr0 = (src_m & 3) * H + hb + (src_m >> 2);   // PyTorch gate row
  const int gr1 = gr0 + 4;
  f16x8 wA[2][32];
  if (layer == 0) {                    // K = 64(x) + 512(h0): frags 0..17
    #pragma unroll
    for (int f = 0; f < 18; ++f) {
      const float *p0, *p1;
      if (f < 2) {
        p0 = Wih0 + (size_t)gr0 * DIN + f * 32 + kgrp * 8;
        p1 = Wih0 + (size_t)gr1 * DIN + f * 32 + kgrp * 8;
      } else {
        p0 = Whh0 + (size_t)gr0 * H + (f - 2) * 32 + kgrp * 8;
        p1 = Whh0 + (size_t)gr1 * H + (f - 2) * 32 + kgrp * 8;
      }
      wA[0][f] = cvt8(p0); wA[1][f] = cvt8(p1);
    }
  } else {                             // K = 512(h0) + 512(h1): frags 0..31
    #pragma unroll
    for (int f = 0; f < 16; ++f) {
      int col = f * 32 + kgrp * 8;
      wA[0][f] = cvt8(Wih1 + (size_t)gr0 * H + col);
      wA[1][f] = cvt8(Wih1 + (size_t)gr1 * H + col);
    }
    #pragma unroll
    for (int f = 16; f < 32; ++f) {
      int col = (f - 16) * 32 + kgrp * 8;
      wA[0][f] = cvt8(Whh1 + (size_t)gr0 * H + col);
      wA[1][f] = cvt8(Whh1 + (size_t)gr1 * H + col);
    }
  }
  float bias[2][4];
  {
    const float* bi = layer ? bih1 : bih0;
    const float* bh = layer ? bhh1 : bhh0;
    #pragma unroll
    for (int t = 0; t < 2; ++t)
      #pragma unroll
      for (int rr = 0; rr < 4; ++rr) {
        int u = hb + t * 4 + kgrp;
        bias[t][rr] = bi[rr * H + u] + bh[rr * H + u];
      }
  }

  // zero both staging buffers once (step 0 reads zeros as h_{-1})
  for (int i = tid; i < 2 * 8320; i += 256) ((unsigned*)sH)[i] = 0;
  __syncthreads();

  float cst0 = 0.f, cst1 = 0.f;
  unsigned spins = 0;                  // cumulative guard (normal use ~1e5)
  const int rowb = bcol * 1040 + kgrp * 16;   // byte offset of B-frag row

  for (int s = 0; s < STEPS; ++s) {
    // x prefetch for L0 waves (frags 0,1)
    float4 xr0 = {0,0,0,0}, xr1 = xr0, xr2 = xr0, xr3 = xr0;
    if (layer == 0) {
      int t = (s < T_SEQ) ? s : (T_SEQ - 1);
      const float* xp = x + ((size_t)((g * 16 + bcol) * T_SEQ + t)) * DIN + kgrp * 8;
      xr0 = *(const float4*)xp;        xr1 = *(const float4*)(xp + 4);
      xr2 = *(const float4*)(xp + 32); xr3 = *(const float4*)(xp + 36);
    }
    // stage tag-s data from slot (s-1)%3 into buf s&1 (2 passes x 16 u64)
    if (s > 0) {
      const unsigned long long* src =
          (const unsigned long long*)(gbase + ((s - 1) % 3) * SLOT_U32);
      const unsigned want = (unsigned)s;
      unsigned* dstbuf = sH[s & 1];
      #pragma unroll
      for (int pass = 0; pass < 2; ++pass) {
        unsigned long long v[16];
        #pragma unroll
        for (int i = 0; i < 16; ++i)
          v[i] = ld_u64(src + tid + (pass * 16 + i) * 256);
        for (;;) {
          unsigned bad = 0;
          #pragma unroll
          for (int i = 0; i < 16; ++i) {
            unsigned lo = (unsigned)v[i], hi = (unsigned)(v[i] >> 32);
            if (((lo >> 16) ^ want) | ((hi >> 16) ^ want)) bad |= (1u << i);
          }
          if (!bad) break;
          if (++spins > 8000000u) break;       // bounded anti-hang guard
          #pragma unroll
          for (int i = 0; i < 16; ++i)
            if (bad & (1u << i))
              v[i] = ld_u64(src + tid + (pass * 16 + i) * 256);
        }
        #pragma unroll
        for (int i = 0; i < 16; ++i) {
          int j = tid + (pass * 16 + i) * 256;   // [2][16][256] u64 index
          unsigned payload = ((unsigned)v[i] & 0xffffu)
                           | ((unsigned)(v[i] >> 32) << 16);
          dstbuf[(j >> 12) * 4160 + ((j >> 8) & 15) * 260 + (j & 255)] = payload;
        }
      }
    }
    __syncthreads();                             // staged; WAR handled by dbuf

    const bool act = layer ? (s > 0) : (s < T_SEQ);
    float hv0 = 0.f, hv1 = 0.f;
    if (act) {
      f32x4 acc0 = {0,0,0,0}, acc1 = {0,0,0,0};
      const char* cur = (const char*)sH[s & 1];
      if (layer == 0) {
        f16x8 b0 = pk8(xr0, xr1);
        acc0 = mfma16(wA[0][0], b0, acc0); acc1 = mfma16(wA[1][0], b0, acc1);
        f16x8 b1 = pk8(xr2, xr3);
        acc0 = mfma16(wA[0][1], b1, acc0); acc1 = mfma16(wA[1][1], b1, acc1);
        #pragma unroll
        for (int f = 2; f < 18; ++f) {
          f16x8 bf = *(const f16x8*)(cur + rowb + (f - 2) * 64);
          acc0 = mfma16(wA[0][f], bf, acc0); acc1 = mfma16(wA[1][f], bf, acc1);
        }
      } else {
        #pragma unroll
        for (int f = 0; f < 16; ++f) {
          f16x8 bf = *(const f16x8*)(cur + rowb + f * 64);
          acc0 = mfma16(wA[0][f], bf, acc0); acc1 = mfma16(wA[1][f], bf, acc1);
        }
        #pragma unroll
        for (int f = 16; f < 32; ++f) {
          f16x8 bf = *(const f16x8*)(cur + 16640 + rowb + (f - 16) * 64);
          acc0 = mfma16(wA[0][f], bf, acc0); acc1 = mfma16(wA[1][f], bf, acc1);
        }
      }
      {
        float ii = sigm(acc0[0] + bias[0][0]);
        float ff = sigm(acc0[1] + bias[0][1]);
        float gg = tanhx(acc0[2] + bias[0][2]);
        float oo = sigm(acc0[3] + bias[0][3]);
        cst0 = ff * cst0 + ii * gg;
        hv0 = oo * tanhx(cst0);
      }
      {
        float ii = sigm(acc1[0] + bias[1][0]);
        float ff = sigm(acc1[1] + bias[1][1]);
        float gg = tanhx(acc1[2] + bias[1][2]);
        float oo = sigm(acc1[3] + bias[1][3]);
        cst1 = ff * cst1 + ii * gg;
        hv1 = oo * tanhx(cst1);
      }
    }
    const bool produce = layer ? true : (s < T_SEQ);   // L1 emits zeros at s=0
    if (produce) {
      unsigned tag = (unsigned)(s + 1) << 16;
      unsigned u0 = (unsigned)__builtin_bit_cast(unsigned short, (_Float16)hv0);
      unsigned u1 = (unsigned)__builtin_bit_cast(unsigned short, (_Float16)hv1);
      unsigned* dst = gbase + (s % 3) * SLOT_U32 + layer * 8192
                    + bcol * 512 + hb + kgrp;
      st_u32(dst,     u0 | tag);                 // unit hb+kgrp
      st_u32(dst + 4, u1 | tag);                 // unit hb+kgrp+4
    }
    // no trailing barrier: next step writes the OTHER LDS buffer
  }

  __syncthreads();                               // main-loop reads done

  // ---- FC epilogue: out = relu([h0_T; h1_T] @ fc_w^T + fc_b), [128][1024]
  {
    const int rt = wid >> 4, ct = wid & 15;      // 8 row-tiles x 16 col-tiles
    const int sg = rt & 3;
    const bool isH1 = (rt >= 4);
    // h0_T: step 1023 -> slot 0, tag 1024; h1_T: step 1024 -> slot 1, tag 1025
    const unsigned want = isH1 ? (unsigned)STEPS : (unsigned)(STEPS - 1);
    const int     slot  = isH1 ? 1 : 0;
    const unsigned long long* src =
        (const unsigned long long*)(ws + sg * GRP_U32 + slot * SLOT_U32
                                    + (isH1 ? 8192 : 0));
    unsigned long long v[16];
    #pragma unroll
    for (int i = 0; i < 16; ++i) v[i] = ld_u64(src + tid + i * 256);
    for (;;) {
      unsigned bad = 0;
      #pragma unroll
      for (int i = 0; i < 16; ++i) {
        unsigned lo = (unsigned)v[i], hi = (unsigned)(v[i] >> 32);
        if (((lo >> 16) ^ want) | ((hi >> 16) ^ want)) bad |= (1u << i);
      }
      if (!bad) break;
      if (++spins > 8000000u) break;
      #pragma unroll
      for (int i = 0; i < 16; ++i)
        if (bad & (1u << i)) v[i] = ld_u64(src + tid + i * 256);
    }
    #pragma unroll
    for (int i = 0; i < 16; ++i) {
      int j = tid + i * 256;                     // [16 batch][256 pairs]
      unsigned payload = ((unsigned)v[i] & 0xffffu)
                       | ((unsigned)(v[i] >> 32) << 16);
      sH[0][(j >> 8) * 260 + (j & 255)] = payload;
    }
    __syncthreads();
    const int col = ct * 64 + wv * 16 + bcol;
    f32x4 a0 = {0,0,0,0}, a1 = {0,0,0,0};
    #pragma unroll
    for (int f = 0; f < 16; ++f) {               // K = 512
      f16x8 af = *(const f16x8*)((const char*)sH[0] + rowb + f * 64);
      f16x8 bf = cvt8(fcw + (size_t)col * H + f * 32 + kgrp * 8);
      if (f & 1) a1 = mfma16(af, bf, a1); else a0 = mfma16(af, bf, a0);
    }
    f32x4 a = a0 + a1;
    const float fb = fcb[col];
    #pragma unroll
    for (int rr = 0; rr < 4; ++rr) {
      int row = rt * 16 + kgrp * 4 + rr;
      float v2 = a[rr] + fb;
      out[(size_t)row * 1024 + col] = v2 > 0.f ? v2 : 0.f;
    }
  }
}

extern "C" void kernel_launch(void* const* d_in, const int* in_sizes, int n_in,
                              void* d_out, int out_size, void* d_ws, size_t ws_size,
                              hipStream_t stream) {
  const float* x    = (const float*)d_in[0];
  const float* Wih0 = (const float*)d_in[1];
  const float* Whh0 = (const float*)d_in[2];
  const float* bih0 = (const float*)d_in[3];
  const float* bhh0 = (const float*)d_in[4];
  const float* Wih1 = (const float*)d_in[5];
  const float* Whh1 = (const float*)d_in[6];
  const float* bih1 = (const float*)d_in[7];
  const float* bhh1 = (const float*)d_in[8];
  const float* fcw  = (const float*)d_in[9];
  const float* fcb  = (const float*)d_in[10];
  (void)in_sizes; (void)n_in; (void)out_size; (void)ws_size;

  // zero tag space every call (tag 0 never matches any wanted tag >= 1)
  hipMemsetAsync(d_ws, 0, WS_BYTES, stream);
  lstm_fused<<<dim3(128), dim3(256), 0, stream>>>(
      x, Wih0, Whh0, bih0, bhh0, Wih1, Whh1, bih1, bhh1, fcw, fcb,
      (float*)d_out, (unsigned*)d_ws);
}

// Round 13
// 4028.766 us; speedup vs baseline: 1.5685x; 1.0464x over previous
//
#include <hip/hip_runtime.h>

// ---------------------------------------------------------------------------
// Persistent fused 2-layer LSTM + FC for MI355X — v13: v6 protocol +
// two serial-chain micro-opts (everything else byte-for-byte v6):
//  (1) pass-1 ring loads ISSUED before pass-0 LDS repack -> repack cost
//      hides under pass-1's LLC RTT (v6 serialized drain-repack-drain).
//  (2) producer stores ONE u64 (even/odd unit pairing, v11-validated
//      mapping) instead of two stride-4 u32s -> half the store
//      transactions -> earlier last-producer visibility.
// Structure (v6, proven 4215 us): 128 WGs x 256 thr (4 waves), 4 groups x
// 32 WGs, 1 WG/CU. wv0/wv1 = L0 (8 units, K=576), wv2/wv3 = L1 (8 units,
// K=1024). Weights resident in VGPRs. h exchange: u32 = fp16|(tag<<16),
// 3-slot agent-scope ring, speculative bulk read + per-word retry,
// double-buffered LDS staging, 1 barrier/step.
// ---------------------------------------------------------------------------

#define H      512
#define T_SEQ  1024
#define DIN    64
#define STEPS  1025

#define SLOT_U32 16384           // [2 layers][16 batch][512 units] tagged u32
#define GRP_U32  49152           // 3 slots
#define WS_BYTES (4 * GRP_U32 * 4)

typedef _Float16 f16x8 __attribute__((ext_vector_type(8)));
typedef float    f32x4 __attribute__((ext_vector_type(4)));
typedef unsigned long long u64t;

__device__ __forceinline__ u64t ld_u64(const u64t* p) {
  return __hip_atomic_load((u64t*)p, __ATOMIC_RELAXED, __HIP_MEMORY_SCOPE_AGENT);
}
__device__ __forceinline__ void st_u64(u64t* p, u64t v) {
  __hip_atomic_store(p, v, __ATOMIC_RELAXED, __HIP_MEMORY_SCOPE_AGENT);
}
__device__ __forceinline__ f16x8 pk8(float4 a, float4 b) {
  f16x8 r;
  r[0] = (_Float16)a.x; r[1] = (_Float16)a.y; r[2] = (_Float16)a.z; r[3] = (_Float16)a.w;
  r[4] = (_Float16)b.x; r[5] = (_Float16)b.y; r[6] = (_Float16)b.z; r[7] = (_Float16)b.w;
  return r;
}
__device__ __forceinline__ f16x8 cvt8(const float* p) {
  return pk8(*(const float4*)p, *(const float4*)(p + 4));
}
__device__ __forceinline__ f32x4 mfma16(f16x8 a, f16x8 b, f32x4 c) {
  return __builtin_amdgcn_mfma_f32_16x16x32_f16(a, b, c, 0, 0, 0);
}
__device__ __forceinline__ float rcpf_(float x) {
#if __has_builtin(__builtin_amdgcn_rcpf)
  return __builtin_amdgcn_rcpf(x);
#else
  return 1.0f / x;
#endif
}
__device__ __forceinline__ float sigm(float x) {
  x = fminf(fmaxf(x, -30.f), 30.f);
  return rcpf_(1.f + __expf(-x));
}
__device__ __forceinline__ float tanhx(float x) {
  x = fminf(fmaxf(x, -15.f), 15.f);
  float e = __expf(2.f * x);
  return (e - 1.f) * rcpf_(e + 1.f);
}
__device__ __forceinline__ unsigned payload(u64t v) {
  return ((unsigned)v & 0xffffu) | ((unsigned)(v >> 32) << 16);
}

__global__ __launch_bounds__(256, 1)
void lstm_fused(const float* __restrict__ x,
                const float* __restrict__ Wih0, const float* __restrict__ Whh0,
                const float* __restrict__ bih0, const float* __restrict__ bhh0,
                const float* __restrict__ Wih1, const float* __restrict__ Whh1,
                const float* __restrict__ bih1, const float* __restrict__ bhh1,
                const float* __restrict__ fcw,  const float* __restrict__ fcb,
                float* __restrict__ out, unsigned* __restrict__ ws)
{
  // double-buffered staged h: [buf][2 layers][16 batch][260 u32]
  __shared__ unsigned sH[2][8320];

  const int tid  = threadIdx.x;
  const int wid  = blockIdx.x;
  const int g    = wid >> 5;           // batch group 0..3
  const int w    = wid & 31;           // WG within group
  const int wv   = tid >> 6;           // wave 0..3
  const int lane = tid & 63;
  const int bcol = lane & 15;          // MFMA N col = batch-in-group
  const int kgrp = lane >> 4;
  const int layer = wv >> 1;
  const int hb    = w * 16 + (wv & 1) * 8;   // 8 units of this wave

  unsigned* gbase = ws + g * GRP_U32;

  // ---- resident weights: 2 M-tiles = even units (hb+2k) / odd (hb+2k+1)
  //      (v11-validated pairing -> one u64 h-store per lane).
  //      M rows gate-interleaved: row m -> gate m&3, unit hb + 2*(m>>2)(+1).
  const int src_m = lane & 15;
  const int gr0 = (src_m & 3) * H + hb + 2 * (src_m >> 2);  // even-unit row
  const int gr1 = gr0 + 1;                                  // odd-unit row
  f16x8 wA[2][32];
  if (layer == 0) {                    // K = 64(x) + 512(h0): frags 0..17
    #pragma unroll
    for (int f = 0; f < 18; ++f) {
      const float *p0, *p1;
      if (f < 2) {
        p0 = Wih0 + (size_t)gr0 * DIN + f * 32 + kgrp * 8;
        p1 = Wih0 + (size_t)gr1 * DIN + f * 32 + kgrp * 8;
      } else {
        p0 = Whh0 + (size_t)gr0 * H + (f - 2) * 32 + kgrp * 8;
        p1 = Whh0 + (size_t)gr1 * H + (f - 2) * 32 + kgrp * 8;
      }
      wA[0][f] = cvt8(p0); wA[1][f] = cvt8(p1);
    }
  } else {                             // K = 512(h0) + 512(h1): frags 0..31
    #pragma unroll
    for (int f = 0; f < 16; ++f) {
      int col = f * 32 + kgrp * 8;
      wA[0][f] = cvt8(Wih1 + (size_t)gr0 * H + col);
      wA[1][f] = cvt8(Wih1 + (size_t)gr1 * H + col);
    }
    #pragma unroll
    for (int f = 16; f < 32; ++f) {
      int col = (f - 16) * 32 + kgrp * 8;
      wA[0][f] = cvt8(Whh1 + (size_t)gr0 * H + col);
      wA[1][f] = cvt8(Whh1 + (size_t)gr1 * H + col);
    }
  }
  float bias[2][4];
  {
    const float* bi = layer ? bih1 : bih0;
    const float* bh = layer ? bhh1 : bhh0;
    const int u0 = hb + 2 * kgrp, u1 = u0 + 1;
    #pragma unroll
    for (int rr = 0; rr < 4; ++rr) {
      bias[0][rr] = bi[rr * H + u0] + bh[rr * H + u0];
      bias[1][rr] = bi[rr * H + u1] + bh[rr * H + u1];
    }
  }

  // zero both staging buffers once (step 0 reads zeros as h_{-1})
  for (int i = tid; i < 2 * 8320; i += 256) ((unsigned*)sH)[i] = 0;
  __syncthreads();

  float cst0 = 0.f, cst1 = 0.f;
  unsigned spins = 0;                  // cumulative guard (normal use ~1e5)
  const int rowb = bcol * 1040 + kgrp * 16;   // byte offset of B-frag row

  for (int s = 0; s < STEPS; ++s) {
    // x prefetch for L0 waves (frags 0,1)
    float4 xr0 = {0,0,0,0}, xr1 = xr0, xr2 = xr0, xr3 = xr0;
    if (layer == 0) {
      int t = (s < T_SEQ) ? s : (T_SEQ - 1);
      const float* xp = x + ((size_t)((g * 16 + bcol) * T_SEQ + t)) * DIN + kgrp * 8;
      xr0 = *(const float4*)xp;        xr1 = *(const float4*)(xp + 4);
      xr2 = *(const float4*)(xp + 32); xr3 = *(const float4*)(xp + 36);
    }
    // stage tag-s data from slot (s-1)%3 into buf s&1.
    // v13 ordering: drain h0 -> ISSUE h1 loads -> repack h0 (hides under
    // h1 RTT) -> drain h1 -> repack h1.  (v6 serialized repack0 before
    // issuing pass 1; the h1 delay itself is load-bearing — v10 lesson.)
    if (s > 0) {
      const u64t* src = (const u64t*)(gbase + ((s - 1) % 3) * SLOT_U32);
      const unsigned want = (unsigned)s;
      unsigned* dstbuf = sH[s & 1];
      u64t v0[16], v1[16];
      #pragma unroll
      for (int i = 0; i < 16; ++i) v0[i] = ld_u64(src + tid + i * 256);
      for (;;) {                                 // verify pass 0 (h0 region)
        unsigned bad = 0;
        #pragma unroll
        for (int i = 0; i < 16; ++i) {
          unsigned lo = (unsigned)v0[i], hi = (unsigned)(v0[i] >> 32);
          if (((lo >> 16) ^ want) | ((hi >> 16) ^ want)) bad |= (1u << i);
        }
        if (!bad) break;
        if (++spins > 8000000u) break;           // bounded anti-hang guard
        #pragma unroll
        for (int i = 0; i < 16; ++i)
          if (bad & (1u << i)) v0[i] = ld_u64(src + tid + i * 256);
      }
      #pragma unroll
      for (int i = 0; i < 16; ++i)               // issue pass 1 (h1 region)
        v1[i] = ld_u64(src + tid + (16 + i) * 256);
      #pragma unroll
      for (int i = 0; i < 16; ++i) {             // repack pass 0 under h1 RTT
        int j = tid + i * 256;                   // [2][16][256] u64 index
        dstbuf[(j >> 12) * 4160 + ((j >> 8) & 15) * 260 + (j & 255)] = payload(v0[i]);
      }
      for (;;) {                                 // verify pass 1
        unsigned bad = 0;
        #pragma unroll
        for (int i = 0; i < 16; ++i) {
          unsigned lo = (unsigned)v1[i], hi = (unsigned)(v1[i] >> 32);
          if (((lo >> 16) ^ want) | ((hi >> 16) ^ want)) bad |= (1u << i);
        }
        if (!bad) break;
        if (++spins > 8000000u) break;
        #pragma unroll
        for (int i = 0; i < 16; ++i)
          if (bad & (1u << i)) v1[i] = ld_u64(src + tid + (16 + i) * 256);
      }
      #pragma unroll
      for (int i = 0; i < 16; ++i) {             // repack pass 1
        int j = tid + (16 + i) * 256;
        dstbuf[(j >> 12) * 4160 + ((j >> 8) & 15) * 260 + (j & 255)] = payload(v1[i]);
      }
    }
    __syncthreads();                             // staged; WAR handled by dbuf

    const bool act = layer ? (s > 0) : (s < T_SEQ);
    float hv0 = 0.f, hv1 = 0.f;
    if (act) {
      f32x4 acc0 = {0,0,0,0}, acc1 = {0,0,0,0};
      const char* cur = (const char*)sH[s & 1];
      if (layer == 0) {
        f16x8 b0 = pk8(xr0, xr1);
        acc0 = mfma16(wA[0][0], b0, acc0); acc1 = mfma16(wA[1][0], b0, acc1);
        f16x8 b1 = pk8(xr2, xr3);
        acc0 = mfma16(wA[0][1], b1, acc0); acc1 = mfma16(wA[1][1], b1, acc1);
        #pragma unroll
        for (int f = 2; f < 18; ++f) {
          f16x8 bf = *(const f16x8*)(cur + rowb + (f - 2) * 64);
          acc0 = mfma16(wA[0][f], bf, acc0); acc1 = mfma16(wA[1][f], bf, acc1);
        }
      } else {
        #pragma unroll
        for (int f = 0; f < 16; ++f) {
          f16x8 bf = *(const f16x8*)(cur + rowb + f * 64);
          acc0 = mfma16(wA[0][f], bf, acc0); acc1 = mfma16(wA[1][f], bf, acc1);
        }
        #pragma unroll
        for (int f = 16; f < 32; ++f) {
          f16x8 bf = *(const f16x8*)(cur + 16640 + rowb + (f - 16) * 64);
          acc0 = mfma16(wA[0][f], bf, acc0); acc1 = mfma16(wA[1][f], bf, acc1);
        }
      }
      {
        float ii = sigm(acc0[0] + bias[0][0]);
        float ff = sigm(acc0[1] + bias[0][1]);
        float gg = tanhx(acc0[2] + bias[0][2]);
        float oo = sigm(acc0[3] + bias[0][3]);
        cst0 = ff * cst0 + ii * gg;
        hv0 = oo * tanhx(cst0);                  // even unit hb+2k
      }
      {
        float ii = sigm(acc1[0] + bias[1][0]);
        float ff = sigm(acc1[1] + bias[1][1]);
        float gg = tanhx(acc1[2] + bias[1][2]);
        float oo = sigm(acc1[3] + bias[1][3]);
        cst1 = ff * cst1 + ii * gg;
        hv1 = oo * tanhx(cst1);                  // odd unit hb+2k+1
      }
    }
    const bool produce = layer ? true : (s < T_SEQ);   // L1 emits zeros at s=0
    if (produce) {
      u64t tag2 = ((u64t)(unsigned)(s + 1) << 16) | ((u64t)(unsigned)(s + 1) << 48);
      u64t e = (u64t)(unsigned)__builtin_bit_cast(unsigned short, (_Float16)hv0);
      u64t o = (u64t)(unsigned)__builtin_bit_cast(unsigned short, (_Float16)hv1);
      u64t* dst = (u64t*)(gbase + (s % 3) * SLOT_U32 + layer * 8192
                          + bcol * 512 + hb) + kgrp;
      st_u64(dst, e | (o << 32) | tag2);         // units hb+2k, hb+2k+1
    }
    // no trailing barrier: next step writes the OTHER LDS buffer
  }

  __syncthreads();                               // main-loop reads done

  // ---- FC epilogue: out = relu([h0_T; h1_T] @ fc_w^T + fc_b), [128][1024]
  {
    const int rt = wid >> 4, ct = wid & 15;      // 8 row-tiles x 16 col-tiles
    const int sg = rt & 3;
    const bool isH1 = (rt >= 4);
    // h0_T: step 1023 -> slot 0, tag 1024; h1_T: step 1024 -> slot 1, tag 1025
    const unsigned want = isH1 ? (unsigned)STEPS : (unsigned)(STEPS - 1);
    const int     slot  = isH1 ? 1 : 0;
    const u64t* src = (const u64t*)(ws + sg * GRP_U32 + slot * SLOT_U32
                                    + (isH1 ? 8192 : 0));
    u64t v[16];
    #pragma unroll
    for (int i = 0; i < 16; ++i) v[i] = ld_u64(src + tid + i * 256);
    for (;;) {
      unsigned bad = 0;
      #pragma unroll
      for (int i = 0; i < 16; ++i) {
        unsigned lo = (unsigned)v[i], hi = (unsigned)(v[i] >> 32);
        if (((lo >> 16) ^ want) | ((hi >> 16) ^ want)) bad |= (1u << i);
      }
      if (!bad) break;
      if (++spins > 8000000u) break;
      #pragma unroll
      for (int i = 0; i < 16; ++i)
        if (bad & (1u << i)) v[i] = ld_u64(src + tid + i * 256);
    }
    #pragma unroll
    for (int i = 0; i < 16; ++i) {
      int j = tid + i * 256;                     // [16 batch][256 pairs]
      sH[0][(j >> 8) * 260 + (j & 255)] = payload(v[i]);
    }
    __syncthreads();
    const int col = ct * 64 + wv * 16 + bcol;
    f32x4 a0 = {0,0,0,0}, a1 = {0,0,0,0};
    #pragma unroll
    for (int f = 0; f < 16; ++f) {               // K = 512
      f16x8 af = *(const f16x8*)((const char*)sH[0] + rowb + f * 64);
      f16x8 bf = cvt8(fcw + (size_t)col * H + f * 32 + kgrp * 8);
      if (f & 1) a1 = mfma16(af, bf, a1); else a0 = mfma16(af, bf, a0);
    }
    f32x4 a = a0 + a1;
    const float fb = fcb[col];
    #pragma unroll
    for (int rr = 0; rr < 4; ++rr) {
      int row = rt * 16 + kgrp * 4 + rr;
      float v2 = a[rr] + fb;
      out[(size_t)row * 1024 + col] = v2 > 0.f ? v2 : 0.f;
    }
  }
}

extern "C" void kernel_launch(void* const* d_in, const int* in_sizes, int n_in,
                              void* d_out, int out_size, void* d_ws, size_t ws_size,
                              hipStream_t stream) {
  const float* x    = (const float*)d_in[0];
  const float* Wih0 = (const float*)d_in[1];
  const float* Whh0 = (const float*)d_in[2];
  const float* bih0 = (const float*)d_in[3];
  const float* bhh0 = (const float*)d_in[4];
  const float* Wih1 = (const float*)d_in[5];
  const float* Whh1 = (const float*)d_in[6];
  const float* bih1 = (const float*)d_in[7];
  const float* bhh1 = (const float*)d_in[8];
  const float* fcw  = (const float*)d_in[9];
  const float* fcb  = (const float*)d_in[10];
  (void)in_sizes; (void)n_in; (void)out_size; (void)ws_size;

  // zero tag space every call (tag 0 never matches any wanted tag >= 1)
  hipMemsetAsync(d_ws, 0, WS_BYTES, stream);
  lstm_fused<<<dim3(128), dim3(256), 0, stream>>>(
      x, Wih0, Whh0, bih0, bhh0, Wih1, Whh1, bih1, bhh1, fcw, fcb,
      (float*)d_out, (unsigned*)d_ws);
}

// Round 14
// 4026.254 us; speedup vs baseline: 1.5695x; 1.0006x over previous
//
#include <hip/hip_runtime.h>

// ---------------------------------------------------------------------------
// Persistent fused 2-layer LSTM + FC for MI355X — v14: v13 + 4-way split
// accumulator chains (only change vs v13).
//  Mechanism: each tile's K-accumulation was ONE serial MFMA dep chain
//  (L1: 32 deps x ~17cy ~= 544cy latency-bound; 2 tiles = only 2-way ILP).
//  Splitting each tile into even/odd-fragment chains gives 4 independent
//  chains -> issue-bound (~320cy): ~220cy off L1's critical path (L1 is the
//  slowest producer and gates h1 availability), ~120cy off L0's.
// v13 recap (4028 us, WRITE halved, no spill):
//  (1) pass-1 ring loads issued before pass-0 LDS repack (repack hides
//      under pass-1 RTT); (2) producer stores ONE u64 (even/odd pairing).
// Structure (v6 lineage): 128 WGs x 256 thr (4 waves), 4 groups x 32 WGs,
// 1 WG/CU. wv0/wv1 = L0 (8 units, K=576), wv2/wv3 = L1 (8 units, K=1024).
// Weights resident in VGPRs. h exchange: u32 = fp16|(tag<<16), 3-slot
// agent-scope ring, speculative bulk read + per-word retry, double-buffered
// LDS staging, 1 barrier/step.
// ---------------------------------------------------------------------------

#define H      512
#define T_SEQ  1024
#define DIN    64
#define STEPS  1025

#define SLOT_U32 16384           // [2 layers][16 batch][512 units] tagged u32
#define GRP_U32  49152           // 3 slots
#define WS_BYTES (4 * GRP_U32 * 4)

typedef _Float16 f16x8 __attribute__((ext_vector_type(8)));
typedef float    f32x4 __attribute__((ext_vector_type(4)));
typedef unsigned long long u64t;

__device__ __forceinline__ u64t ld_u64(const u64t* p) {
  return __hip_atomic_load((u64t*)p, __ATOMIC_RELAXED, __HIP_MEMORY_SCOPE_AGENT);
}
__device__ __forceinline__ void st_u64(u64t* p, u64t v) {
  __hip_atomic_store(p, v, __ATOMIC_RELAXED, __HIP_MEMORY_SCOPE_AGENT);
}
__device__ __forceinline__ f16x8 pk8(float4 a, float4 b) {
  f16x8 r;
  r[0] = (_Float16)a.x; r[1] = (_Float16)a.y; r[2] = (_Float16)a.z; r[3] = (_Float16)a.w;
  r[4] = (_Float16)b.x; r[5] = (_Float16)b.y; r[6] = (_Float16)b.z; r[7] = (_Float16)b.w;
  return r;
}
__device__ __forceinline__ f16x8 cvt8(const float* p) {
  return pk8(*(const float4*)p, *(const float4*)(p + 4));
}
__device__ __forceinline__ f32x4 mfma16(f16x8 a, f16x8 b, f32x4 c) {
  return __builtin_amdgcn_mfma_f32_16x16x32_f16(a, b, c, 0, 0, 0);
}
__device__ __forceinline__ float rcpf_(float x) {
#if __has_builtin(__builtin_amdgcn_rcpf)
  return __builtin_amdgcn_rcpf(x);
#else
  return 1.0f / x;
#endif
}
__device__ __forceinline__ float sigm(float x) {
  x = fminf(fmaxf(x, -30.f), 30.f);
  return rcpf_(1.f + __expf(-x));
}
__device__ __forceinline__ float tanhx(float x) {
  x = fminf(fmaxf(x, -15.f), 15.f);
  float e = __expf(2.f * x);
  return (e - 1.f) * rcpf_(e + 1.f);
}
__device__ __forceinline__ unsigned payload(u64t v) {
  return ((unsigned)v & 0xffffu) | ((unsigned)(v >> 32) << 16);
}

__global__ __launch_bounds__(256, 1)
void lstm_fused(const float* __restrict__ x,
                const float* __restrict__ Wih0, const float* __restrict__ Whh0,
                const float* __restrict__ bih0, const float* __restrict__ bhh0,
                const float* __restrict__ Wih1, const float* __restrict__ Whh1,
                const float* __restrict__ bih1, const float* __restrict__ bhh1,
                const float* __restrict__ fcw,  const float* __restrict__ fcb,
                float* __restrict__ out, unsigned* __restrict__ ws)
{
  // double-buffered staged h: [buf][2 layers][16 batch][260 u32]
  __shared__ unsigned sH[2][8320];

  const int tid  = threadIdx.x;
  const int wid  = blockIdx.x;
  const int g    = wid >> 5;           // batch group 0..3
  const int w    = wid & 31;           // WG within group
  const int wv   = tid >> 6;           // wave 0..3
  const int lane = tid & 63;
  const int bcol = lane & 15;          // MFMA N col = batch-in-group
  const int kgrp = lane >> 4;
  const int layer = wv >> 1;
  const int hb    = w * 16 + (wv & 1) * 8;   // 8 units of this wave

  unsigned* gbase = ws + g * GRP_U32;

  // ---- resident weights: 2 M-tiles = even units (hb+2k) / odd (hb+2k+1)
  //      (pairing -> one u64 h-store per lane).
  //      M rows gate-interleaved: row m -> gate m&3, unit hb + 2*(m>>2)(+1).
  const int src_m = lane & 15;
  const int gr0 = (src_m & 3) * H + hb + 2 * (src_m >> 2);  // even-unit row
  const int gr1 = gr0 + 1;                                  // odd-unit row
  f16x8 wA[2][32];
  if (layer == 0) {                    // K = 64(x) + 512(h0): frags 0..17
    #pragma unroll
    for (int f = 0; f < 18; ++f) {
      const float *p0, *p1;
      if (f < 2) {
        p0 = Wih0 + (size_t)gr0 * DIN + f * 32 + kgrp * 8;
        p1 = Wih0 + (size_t)gr1 * DIN + f * 32 + kgrp * 8;
      } else {
        p0 = Whh0 + (size_t)gr0 * H + (f - 2) * 32 + kgrp * 8;
        p1 = Whh0 + (size_t)gr1 * H + (f - 2) * 32 + kgrp * 8;
      }
      wA[0][f] = cvt8(p0); wA[1][f] = cvt8(p1);
    }
  } else {                             // K = 512(h0) + 512(h1): frags 0..31
    #pragma unroll
    for (int f = 0; f < 16; ++f) {
      int col = f * 32 + kgrp * 8;
      wA[0][f] = cvt8(Wih1 + (size_t)gr0 * H + col);
      wA[1][f] = cvt8(Wih1 + (size_t)gr1 * H + col);
    }
    #pragma unroll
    for (int f = 16; f < 32; ++f) {
      int col = (f - 16) * 32 + kgrp * 8;
      wA[0][f] = cvt8(Whh1 + (size_t)gr0 * H + col);
      wA[1][f] = cvt8(Whh1 + (size_t)gr1 * H + col);
    }
  }
  float bias[2][4];
  {
    const float* bi = layer ? bih1 : bih0;
    const float* bh = layer ? bhh1 : bhh0;
    const int u0 = hb + 2 * kgrp, u1 = u0 + 1;
    #pragma unroll
    for (int rr = 0; rr < 4; ++rr) {
      bias[0][rr] = bi[rr * H + u0] + bh[rr * H + u0];
      bias[1][rr] = bi[rr * H + u1] + bh[rr * H + u1];
    }
  }

  // zero both staging buffers once (step 0 reads zeros as h_{-1})
  for (int i = tid; i < 2 * 8320; i += 256) ((unsigned*)sH)[i] = 0;
  __syncthreads();

  float cst0 = 0.f, cst1 = 0.f;
  unsigned spins = 0;                  // cumulative guard (normal use ~1e5)
  const int rowb = bcol * 1040 + kgrp * 16;   // byte offset of B-frag row

  for (int s = 0; s < STEPS; ++s) {
    // x prefetch for L0 waves (frags 0,1)
    float4 xr0 = {0,0,0,0}, xr1 = xr0, xr2 = xr0, xr3 = xr0;
    if (layer == 0) {
      int t = (s < T_SEQ) ? s : (T_SEQ - 1);
      const float* xp = x + ((size_t)((g * 16 + bcol) * T_SEQ + t)) * DIN + kgrp * 8;
      xr0 = *(const float4*)xp;        xr1 = *(const float4*)(xp + 4);
      xr2 = *(const float4*)(xp + 32); xr3 = *(const float4*)(xp + 36);
    }
    // stage tag-s data from slot (s-1)%3 into buf s&1:
    // drain h0 -> ISSUE h1 loads -> repack h0 (hidden under h1 RTT) ->
    // drain h1 -> repack h1.  (h1's delayed issue is load-bearing — v10.)
    if (s > 0) {
      const u64t* src = (const u64t*)(gbase + ((s - 1) % 3) * SLOT_U32);
      const unsigned want = (unsigned)s;
      unsigned* dstbuf = sH[s & 1];
      u64t v0[16], v1[16];
      #pragma unroll
      for (int i = 0; i < 16; ++i) v0[i] = ld_u64(src + tid + i * 256);
      for (;;) {                                 // verify pass 0 (h0 region)
        unsigned bad = 0;
        #pragma unroll
        for (int i = 0; i < 16; ++i) {
          unsigned lo = (unsigned)v0[i], hi = (unsigned)(v0[i] >> 32);
          if (((lo >> 16) ^ want) | ((hi >> 16) ^ want)) bad |= (1u << i);
        }
        if (!bad) break;
        if (++spins > 8000000u) break;           // bounded anti-hang guard
        #pragma unroll
        for (int i = 0; i < 16; ++i)
          if (bad & (1u << i)) v0[i] = ld_u64(src + tid + i * 256);
      }
      #pragma unroll
      for (int i = 0; i < 16; ++i)               // issue pass 1 (h1 region)
        v1[i] = ld_u64(src + tid + (16 + i) * 256);
      #pragma unroll
      for (int i = 0; i < 16; ++i) {             // repack pass 0 under h1 RTT
        int j = tid + i * 256;                   // [2][16][256] u64 index
        dstbuf[(j >> 12) * 4160 + ((j >> 8) & 15) * 260 + (j & 255)] = payload(v0[i]);
      }
      for (;;) {                                 // verify pass 1
        unsigned bad = 0;
        #pragma unroll
        for (int i = 0; i < 16; ++i) {
          unsigned lo = (unsigned)v1[i], hi = (unsigned)(v1[i] >> 32);
          if (((lo >> 16) ^ want) | ((hi >> 16) ^ want)) bad |= (1u << i);
        }
        if (!bad) break;
        if (++spins > 8000000u) break;
        #pragma unroll
        for (int i = 0; i < 16; ++i)
          if (bad & (1u << i)) v1[i] = ld_u64(src + tid + (16 + i) * 256);
      }
      #pragma unroll
      for (int i = 0; i < 16; ++i) {             // repack pass 1
        int j = tid + (16 + i) * 256;
        dstbuf[(j >> 12) * 4160 + ((j >> 8) & 15) * 260 + (j & 255)] = payload(v1[i]);
      }
    }
    __syncthreads();                             // staged; WAR handled by dbuf

    const bool act = layer ? (s > 0) : (s < T_SEQ);
    float hv0 = 0.f, hv1 = 0.f;
    if (act) {
      // 4 independent accumulator chains (even/odd frags x 2 tiles):
      // crosses the issue-bound threshold (4x5cy issue >= ~17cy latency).
      f32x4 a0e = {0,0,0,0}, a0o = {0,0,0,0};
      f32x4 a1e = {0,0,0,0}, a1o = {0,0,0,0};
      const char* cur = (const char*)sH[s & 1];
      if (layer == 0) {
        f16x8 b0 = pk8(xr0, xr1);
        a0e = mfma16(wA[0][0], b0, a0e); a1e = mfma16(wA[1][0], b0, a1e);
        f16x8 b1 = pk8(xr2, xr3);
        a0o = mfma16(wA[0][1], b1, a0o); a1o = mfma16(wA[1][1], b1, a1o);
        #pragma unroll
        for (int f = 2; f < 18; ++f) {
          f16x8 bf = *(const f16x8*)(cur + rowb + (f - 2) * 64);
          if (f & 1) { a0o = mfma16(wA[0][f], bf, a0o); a1o = mfma16(wA[1][f], bf, a1o); }
          else       { a0e = mfma16(wA[0][f], bf, a0e); a1e = mfma16(wA[1][f], bf, a1e); }
        }
      } else {
        #pragma unroll
        for (int f = 0; f < 16; ++f) {
          f16x8 bf = *(const f16x8*)(cur + rowb + f * 64);
          if (f & 1) { a0o = mfma16(wA[0][f], bf, a0o); a1o = mfma16(wA[1][f], bf, a1o); }
          else       { a0e = mfma16(wA[0][f], bf, a0e); a1e = mfma16(wA[1][f], bf, a1e); }
        }
        #pragma unroll
        for (int f = 16; f < 32; ++f) {
          f16x8 bf = *(const f16x8*)(cur + 16640 + rowb + (f - 16) * 64);
          if (f & 1) { a0o = mfma16(wA[0][f], bf, a0o); a1o = mfma16(wA[1][f], bf, a1o); }
          else       { a0e = mfma16(wA[0][f], bf, a0e); a1e = mfma16(wA[1][f], bf, a1e); }
        }
      }
      f32x4 acc0 = a0e + a0o;
      f32x4 acc1 = a1e + a1o;
      {
        float ii = sigm(acc0[0] + bias[0][0]);
        float ff = sigm(acc0[1] + bias[0][1]);
        float gg = tanhx(acc0[2] + bias[0][2]);
        float oo = sigm(acc0[3] + bias[0][3]);
        cst0 = ff * cst0 + ii * gg;
        hv0 = oo * tanhx(cst0);                  // even unit hb+2k
      }
      {
        float ii = sigm(acc1[0] + bias[1][0]);
        float ff = sigm(acc1[1] + bias[1][1]);
        float gg = tanhx(acc1[2] + bias[1][2]);
        float oo = sigm(acc1[3] + bias[1][3]);
        cst1 = ff * cst1 + ii * gg;
        hv1 = oo * tanhx(cst1);                  // odd unit hb+2k+1
      }
    }
    const bool produce = layer ? true : (s < T_SEQ);   // L1 emits zeros at s=0
    if (produce) {
      u64t tag2 = ((u64t)(unsigned)(s + 1) << 16) | ((u64t)(unsigned)(s + 1) << 48);
      u64t e = (u64t)(unsigned)__builtin_bit_cast(unsigned short, (_Float16)hv0);
      u64t o = (u64t)(unsigned)__builtin_bit_cast(unsigned short, (_Float16)hv1);
      u64t* dst = (u64t*)(gbase + (s % 3) * SLOT_U32 + layer * 8192
                          + bcol * 512 + hb) + kgrp;
      st_u64(dst, e | (o << 32) | tag2);         // units hb+2k, hb+2k+1
    }
    // no trailing barrier: next step writes the OTHER LDS buffer
  }

  __syncthreads();                               // main-loop reads done

  // ---- FC epilogue: out = relu([h0_T; h1_T] @ fc_w^T + fc_b), [128][1024]
  {
    const int rt = wid >> 4, ct = wid & 15;      // 8 row-tiles x 16 col-tiles
    const int sg = rt & 3;
    const bool isH1 = (rt >= 4);
    // h0_T: step 1023 -> slot 0, tag 1024; h1_T: step 1024 -> slot 1, tag 1025
    const unsigned want = isH1 ? (unsigned)STEPS : (unsigned)(STEPS - 1);
    const int     slot  = isH1 ? 1 : 0;
    const u64t* src = (const u64t*)(ws + sg * GRP_U32 + slot * SLOT_U32
                                    + (isH1 ? 8192 : 0));
    u64t v[16];
    #pragma unroll
    for (int i = 0; i < 16; ++i) v[i] = ld_u64(src + tid + i * 256);
    for (;;) {
      unsigned bad = 0;
      #pragma unroll
      for (int i = 0; i < 16; ++i) {
        unsigned lo = (unsigned)v[i], hi = (unsigned)(v[i] >> 32);
        if (((lo >> 16) ^ want) | ((hi >> 16) ^ want)) bad |= (1u << i);
      }
      if (!bad) break;
      if (++spins > 8000000u) break;
      #pragma unroll
      for (int i = 0; i < 16; ++i)
        if (bad & (1u << i)) v[i] = ld_u64(src + tid + i * 256);
    }
    #pragma unroll
    for (int i = 0; i < 16; ++i) {
      int j = tid + i * 256;                     // [16 batch][256 pairs]
      sH[0][(j >> 8) * 260 + (j & 255)] = payload(v[i]);
    }
    __syncthreads();
    const int col = ct * 64 + wv * 16 + bcol;
    f32x4 a0 = {0,0,0,0}, a1 = {0,0,0,0};
    #pragma unroll
    for (int f = 0; f < 16; ++f) {               // K = 512
      f16x8 af = *(const f16x8*)((const char*)sH[0] + rowb + f * 64);
      f16x8 bf = cvt8(fcw + (size_t)col * H + f * 32 + kgrp * 8);
      if (f & 1) a1 = mfma16(af, bf, a1); else a0 = mfma16(af, bf, a0);
    }
    f32x4 a = a0 + a1;
    const float fb = fcb[col];
    #pragma unroll
    for (int rr = 0; rr < 4; ++rr) {
      int row = rt * 16 + kgrp * 4 + rr;
      float v2 = a[rr] + fb;
      out[(size_t)row * 1024 + col] = v2 > 0.f ? v2 : 0.f;
    }
  }
}

extern "C" void kernel_launch(void* const* d_in, const int* in_sizes, int n_in,
                              void* d_out, int out_size, void* d_ws, size_t ws_size,
                              hipStream_t stream) {
  const float* x    = (const float*)d_in[0];
  const float* Wih0 = (const float*)d_in[1];
  const float* Whh0 = (const float*)d_in[2];
  const float* bih0 = (const float*)d_in[3];
  const float* bhh0 = (const float*)d_in[4];
  const float* Wih1 = (const float*)d_in[5];
  const float* Whh1 = (const float*)d_in[6];
  const float* bih1 = (const float*)d_in[7];
  const float* bhh1 = (const float*)d_in[8];
  const float* fcw  = (const float*)d_in[9];
  const float* fcb  = (const float*)d_in[10];
  (void)in_sizes; (void)n_in; (void)out_size; (void)ws_size;

  // zero tag space every call (tag 0 never matches any wanted tag >= 1)
  hipMemsetAsync(d_ws, 0, WS_BYTES, stream);
  lstm_fused<<<dim3(128), dim3(256), 0, stream>>>(
      x, Wih0, Whh0, bih0, bhh0, Wih1, Whh1, bih1, bhh1, fcw, fcb,
      (float*)d_out, (unsigned*)d_ws);
}